// Round 4
// baseline (9565.382 us; speedup 1.0000x reference)
//
#include <hip/hip_runtime.h>
#include <hip/hip_bf16.h>

#define TT  512
#define BB  64
#define NII 1024
#define NHH 1024
#define NBLK 256

typedef __attribute__((ext_vector_type(8))) short bf16x8;
typedef __attribute__((ext_vector_type(4))) float f32x4;

#define WPK_BYTES (256ull * 64 * 64 * 8 * 2)          // 16 MiB packed weights
#define HPK_BYTES (4ull * 32 * 64 * 8 * 2)            // 128 KiB packed H frags
#define FLG_BYTES (4096ull)                           // 256 u32 flags (+pad)
#define XPK_BYTES (512ull * 4 * 32 * 64 * 8 * 2)      // 64 MiB packed x frags

#define MFMA16 __builtin_amdgcn_mfma_f32_16x16x32_bf16

__device__ __forceinline__ float sigmoidf_(float x) { return 1.0f / (1.0f + __expf(-x)); }

__device__ __forceinline__ short f2bf(float f) {
    union { __hip_bfloat16 b; short s; } u; u.b = __float2bfloat16(f); return u.s;
}

// device-coherent (bypass L1/L2) 16B load as two volatile u64 loads
__device__ __forceinline__ bf16x8 ldcg(const short* p) {
    const volatile unsigned long long* q = (const volatile unsigned long long*)p;
    unsigned long long a = q[0];
    unsigned long long b = q[1];
    union { unsigned long long u[2]; bf16x8 v; } u;
    u.u[0] = a; u.u[1] = b; return u.v;
}

// ---------------------------------------------------------------------------
// Pack 8 weight matrices into MFMA-B-fragment-major bf16 (verified r2/r3).
// ---------------------------------------------------------------------------
__global__ __launch_bounds__(256)
void pack_weights_kernel(const float* __restrict__ Wxf, const float* __restrict__ Whf,
                         const float* __restrict__ Wxi, const float* __restrict__ Whi,
                         const float* __restrict__ Wxc, const float* __restrict__ Whc,
                         const float* __restrict__ Wxo, const float* __restrict__ Who,
                         short* __restrict__ wpk)
{
    const int b = blockIdx.x;
    const int t = threadIdx.x;
    const float* Wx[4] = { Wxf, Wxi, Wxc, Wxo };
    const float* Wh[4] = { Whf, Whi, Whc, Who };

    for (int i = 0; i < 16; ++i) {
        const int pair = t + i * 256;
        const int kk = pair >> 6;
        const int l  = pair & 63;
        const int n  = l & 15;
        const int g  = n >> 2;
        const int col = b * 4 + (n & 3);
        const int kf0 = kk * 32 + (l >> 4) * 8;
        const float* src = (kf0 < 1024) ? (Wx[g] + (size_t)kf0 * NHH + col)
                                        : (Wh[g] + (size_t)(kf0 - 1024) * NHH + col);
        short v[8];
        #pragma unroll
        for (int e = 0; e < 8; ++e) v[e] = f2bf(src[(size_t)e * NHH]);
        short* dst = wpk + ((size_t)(b * 64 + kk) * 64 + l) * 8;
        *reinterpret_cast<bf16x8*>(dst) = *reinterpret_cast<bf16x8*>(v);
    }
}

// ---------------------------------------------------------------------------
// Pack x into bf16 A-fragments: xpk[t][mi][kk][l][8] (verified r3).
// ---------------------------------------------------------------------------
__global__ __launch_bounds__(256)
void pack_x_kernel(const float* __restrict__ x, short* __restrict__ xpk)
{
    const int t = blockIdx.x;
    const float* xt = x + (size_t)t * BB * NII;
    short* dst = xpk + (size_t)t * 65536;

    for (int i = 0; i < 32; ++i) {
        const int d  = threadIdx.x + i * 256;
        const int mi = d >> 11;
        const int kk = (d >> 6) & 31;
        const int l  = d & 63;
        const int m  = mi * 16 + (l & 15);
        const int k0 = kk * 32 + ((l >> 4) << 3);
        const float* s = xt + (size_t)m * NII + k0;
        f32x4 a0 = *reinterpret_cast<const f32x4*>(s);
        f32x4 a1 = *reinterpret_cast<const f32x4*>(s + 4);
        short v[8];
        #pragma unroll
        for (int e = 0; e < 4; ++e) { v[e] = f2bf(a0[e]); v[4 + e] = f2bf(a1[e]); }
        *reinterpret_cast<bf16x8*>(dst + (size_t)d * 8) = *reinterpret_cast<bf16x8*>(v);
    }
}

// ---------------------------------------------------------------------------
// Persistent LSTM. 256 blocks x 512 threads, 1 block/CU (LDS-forced).
// Per step: kh=0 waves compute x-half immediately; kh=1 waves poll the 256
// distributed flags (H published), then compute h-half; epilogue fuses
// partials + gates + C/H update; wave0 publishes packed H and sets its flag.
// ---------------------------------------------------------------------------
__global__ __launch_bounds__(512, 1)
void lstm_persistent(const float* __restrict__ x,
                     const short* __restrict__ xpk,
                     const short* __restrict__ wpk,
                     const float* __restrict__ bfv, const float* __restrict__ biv,
                     const float* __restrict__ bcv, const float* __restrict__ bov,
                     float* __restrict__ out,
                     short* __restrict__ hpk0, short* __restrict__ hpk1,
                     unsigned* __restrict__ flags,
                     int use_xpk)
{
    __shared__ short lds_w[64 * 64 * 8];   // 64 KiB weights, frag-major
    __shared__ float redx[4][64][4];       // x-half partials
    __shared__ float redh[4][64][4];       // h-half partials
    __shared__ float Cst[256];
    __shared__ short hstage[256];
    extern __shared__ char dynpad[];

    const int tid = threadIdx.x;
    const int w   = tid >> 6;
    const int l   = tid & 63;
    const int mi  = w & 3;
    const int kh  = w >> 2;
    const int b   = blockIdx.x;
    (void)dynpad;

    {
        const short* wsrc = wpk + (size_t)b * 32768;
        #pragma unroll
        for (int i = 0; i < 8; ++i) {
            const int c = tid + i * 512;
            *reinterpret_cast<bf16x8*>(&lds_w[c * 8]) =
                *reinterpret_cast<const bf16x8*>(&wsrc[(size_t)c * 8]);
        }
    }
    if (tid < 256) Cst[tid] = 0.0f;

    float B4[4] = {0.f, 0.f, 0.f, 0.f};
    if (tid < 256) {
        const int j = b * 4 + (tid & 3);
        B4[0] = bfv[j]; B4[1] = biv[j]; B4[2] = bcv[j]; B4[3] = bov[j];
    }
    __syncthreads();

    // packed-H write coords (j-range b*4..b*4+3 lies in one fragment octet)
    const int kk2 = b >> 3;
    const int lg  = (b >> 1) & 3;
    const int e0  = (b & 1) * 4;

    #pragma unroll 1
    for (int t = 0; t < TT; ++t) {
        const short* hpk_cur = (t & 1) ? hpk1 : hpk0;
        short*       hpk_nxt = (t & 1) ? hpk0 : hpk1;
        const unsigned tv = (unsigned)t;

        if (kh == 0) {
            f32x4 ac0 = {0,0,0,0}, ac1 = {0,0,0,0}, ac2 = {0,0,0,0}, ac3 = {0,0,0,0};
            const short* wl = &lds_w[(size_t)l * 8];
            if (use_xpk) {
                const short* ap = xpk + (size_t)t * 65536 + ((size_t)(mi * 32) * 64 + l) * 8;
                #pragma unroll 2
                for (int kk = 0; kk < 32; kk += 4) {
                    bf16x8 a0 = *reinterpret_cast<const bf16x8*>(ap);
                    bf16x8 b0 = *reinterpret_cast<const bf16x8*>(wl);
                    bf16x8 a1 = *reinterpret_cast<const bf16x8*>(ap + 512);
                    bf16x8 b1 = *reinterpret_cast<const bf16x8*>(wl + 512);
                    bf16x8 a2 = *reinterpret_cast<const bf16x8*>(ap + 1024);
                    bf16x8 b2 = *reinterpret_cast<const bf16x8*>(wl + 1024);
                    bf16x8 a3 = *reinterpret_cast<const bf16x8*>(ap + 1536);
                    bf16x8 b3 = *reinterpret_cast<const bf16x8*>(wl + 1536);
                    ac0 = MFMA16(a0, b0, ac0, 0, 0, 0);
                    ac1 = MFMA16(a1, b1, ac1, 0, 0, 0);
                    ac2 = MFMA16(a2, b2, ac2, 0, 0, 0);
                    ac3 = MFMA16(a3, b3, ac3, 0, 0, 0);
                    ap += 2048; wl += 2048;
                }
            } else {
                const float* apf = x + (size_t)t * BB * NII + (size_t)(mi * 16 + (l & 15)) * NII + (l >> 4) * 8;
                #pragma unroll 2
                for (int kk = 0; kk < 32; kk += 2) {
                    f32x4 a0 = *reinterpret_cast<const f32x4*>(apf);
                    f32x4 a1 = *reinterpret_cast<const f32x4*>(apf + 4);
                    bf16x8 b0 = *reinterpret_cast<const bf16x8*>(wl);
                    f32x4 a2 = *reinterpret_cast<const f32x4*>(apf + 32);
                    f32x4 a3 = *reinterpret_cast<const f32x4*>(apf + 36);
                    bf16x8 b1 = *reinterpret_cast<const bf16x8*>(wl + 512);
                    bf16x8 f0, f1;
                    f0[0]=f2bf(a0[0]); f0[1]=f2bf(a0[1]); f0[2]=f2bf(a0[2]); f0[3]=f2bf(a0[3]);
                    f0[4]=f2bf(a1[0]); f0[5]=f2bf(a1[1]); f0[6]=f2bf(a1[2]); f0[7]=f2bf(a1[3]);
                    f1[0]=f2bf(a2[0]); f1[1]=f2bf(a2[1]); f1[2]=f2bf(a2[2]); f1[3]=f2bf(a2[3]);
                    f1[4]=f2bf(a3[0]); f1[5]=f2bf(a3[1]); f1[6]=f2bf(a3[2]); f1[7]=f2bf(a3[3]);
                    ac0 = MFMA16(f0, b0, ac0, 0, 0, 0);
                    ac1 = MFMA16(f1, b1, ac1, 0, 0, 0);
                    apf += 64; wl += 1024;
                }
            }
            ac0[0]+=ac1[0]+ac2[0]+ac3[0]; ac0[1]+=ac1[1]+ac2[1]+ac3[1];
            ac0[2]+=ac1[2]+ac2[2]+ac3[2]; ac0[3]+=ac1[3]+ac2[3]+ac3[3];
            redx[mi][l][0]=ac0[0]; redx[mi][l][1]=ac0[1];
            redx[mi][l][2]=ac0[2]; redx[mi][l][3]=ac0[3];
        } else {
            // wait until every block has published H for this step
            for (;;) {
                const unsigned long long* q = (const unsigned long long*)(flags + l * 4);
                unsigned long long aa = __hip_atomic_load(q,     __ATOMIC_RELAXED, __HIP_MEMORY_SCOPE_AGENT);
                unsigned long long bb = __hip_atomic_load(q + 1, __ATOMIC_RELAXED, __HIP_MEMORY_SCOPE_AGENT);
                int ok = ((unsigned)aa >= tv) & ((unsigned)(aa >> 32) >= tv) &
                         ((unsigned)bb >= tv) & ((unsigned)(bb >> 32) >= tv);
                if (__all(ok)) break;
            }
            f32x4 ac0 = {0,0,0,0}, ac1 = {0,0,0,0}, ac2 = {0,0,0,0}, ac3 = {0,0,0,0};
            const short* ap = hpk_cur + ((size_t)(mi * 32) * 64 + l) * 8;
            const short* wl = &lds_w[((size_t)(32 * 64) + l) * 8];
            #pragma unroll 2
            for (int kk = 0; kk < 32; kk += 4) {
                bf16x8 a0 = ldcg(ap);
                bf16x8 b0 = *reinterpret_cast<const bf16x8*>(wl);
                bf16x8 a1 = ldcg(ap + 512);
                bf16x8 b1 = *reinterpret_cast<const bf16x8*>(wl + 512);
                bf16x8 a2 = ldcg(ap + 1024);
                bf16x8 b2 = *reinterpret_cast<const bf16x8*>(wl + 1024);
                bf16x8 a3 = ldcg(ap + 1536);
                bf16x8 b3 = *reinterpret_cast<const bf16x8*>(wl + 1536);
                ac0 = MFMA16(a0, b0, ac0, 0, 0, 0);
                ac1 = MFMA16(a1, b1, ac1, 0, 0, 0);
                ac2 = MFMA16(a2, b2, ac2, 0, 0, 0);
                ac3 = MFMA16(a3, b3, ac3, 0, 0, 0);
                ap += 2048; wl += 2048;
            }
            ac0[0]+=ac1[0]+ac2[0]+ac3[0]; ac0[1]+=ac1[1]+ac2[1]+ac3[1];
            ac0[2]+=ac1[2]+ac2[2]+ac3[2]; ac0[3]+=ac1[3]+ac2[3]+ac3[3];
            redh[mi][l][0]=ac0[0]; redh[mi][l][1]=ac0[1];
            redh[mi][l][2]=ac0[2]; redh[mi][l][3]=ac0[3];
        }
        __syncthreads();

        if (tid < 256) {
            const int m   = tid >> 2;
            const int jl  = tid & 3;
            const int mi2 = m >> 4, ml = m & 15;
            const int lr  = ml & 3;
            const int lb  = (ml >> 2) << 4;
            const int j   = b * 4 + jl;

            const float gf = redx[mi2][lb + jl][lr]      + redh[mi2][lb + jl][lr]      + B4[0];
            const float gi = redx[mi2][lb + 4 + jl][lr]  + redh[mi2][lb + 4 + jl][lr]  + B4[1];
            const float gc = redx[mi2][lb + 8 + jl][lr]  + redh[mi2][lb + 8 + jl][lr]  + B4[2];
            const float go = redx[mi2][lb + 12 + jl][lr] + redh[mi2][lb + 12 + jl][lr] + B4[3];

            const float F  = sigmoidf_(gf);
            const float I  = sigmoidf_(gi);
            const float Ct = tanhf(gc);
            const float O  = sigmoidf_(go);

            const float c  = Cst[tid];
            const float cn = F * c + I * Ct;
            const float hn = O * tanhf(cn);
            Cst[tid]    = cn;
            hstage[tid] = f2bf(hn);

            __builtin_nontemporal_store(hn, &out[(size_t)t * BB * NHH + (size_t)m * NHH + j]);
            if (t == TT - 1) {
                float* tail = out + (size_t)TT * BB * NHH;
                tail[(size_t)m * NHH + j]                    = hn;
                tail[(size_t)BB * NHH + (size_t)m * NHH + j] = cn;
            }
        }
        __syncthreads();

        if (w == 0) {
            const int mi2 = l >> 4, ml = l & 15;
            const unsigned long long hv =
                *reinterpret_cast<const unsigned long long*>(&hstage[l * 4]);
            const size_t off = ((size_t)(mi2 * 32 + kk2) * 64 + lg * 16 + ml) * 8 + e0;
            *(volatile unsigned long long*)(hpk_nxt + off) = hv;
            asm volatile("s_waitcnt vmcnt(0)" ::: "memory");
            if (l == 0)
                __hip_atomic_store(&flags[b], tv + 1u, __ATOMIC_RELAXED, __HIP_MEMORY_SCOPE_AGENT);
        }
        // no further block-wide sync needed: next step's LDS writes are gated
        // by this step's __syncthreads pair (see hazard analysis in notes)
    }
}

extern "C" void kernel_launch(void* const* d_in, const int* in_sizes, int n_in,
                              void* d_out, int out_size, void* d_ws, size_t ws_size,
                              hipStream_t stream) {
    const float* inputs = (const float*)d_in[0];
    const float* Wxf = (const float*)d_in[1],  *Whf = (const float*)d_in[2],  *bf = (const float*)d_in[3];
    const float* Wxi = (const float*)d_in[4],  *Whi = (const float*)d_in[5],  *bi = (const float*)d_in[6];
    const float* Wxc = (const float*)d_in[7],  *Whc = (const float*)d_in[8],  *bc = (const float*)d_in[9];
    const float* Wxo = (const float*)d_in[10], *Who = (const float*)d_in[11], *bo = (const float*)d_in[12];

    float* out = (float*)d_out;
    char*  wsb = (char*)d_ws;

    short*    wpk   = (short*)wsb;
    short*    hpk0  = (short*)(wsb + WPK_BYTES);
    short*    hpk1  = (short*)(wsb + WPK_BYTES + HPK_BYTES);
    unsigned* flags = (unsigned*)(wsb + WPK_BYTES + 2 * HPK_BYTES);
    short*    xpk   = (short*)(wsb + WPK_BYTES + 2 * HPK_BYTES + FLG_BYTES);

    const size_t need = WPK_BYTES + 2 * HPK_BYTES + FLG_BYTES + XPK_BYTES;
    const int use_xpk = (ws_size >= need) ? 1 : 0;

    // zero H0 ping-pong + flags every launch (graph replays re-run this)
    hipMemsetAsync(hpk0, 0, 2 * HPK_BYTES + FLG_BYTES, stream);

    pack_weights_kernel<<<dim3(256), dim3(256), 0, stream>>>(
        Wxf, Whf, Wxi, Whi, Wxc, Whc, Wxo, Who, wpk);

    if (use_xpk)
        pack_x_kernel<<<dim3(TT), dim3(256), 0, stream>>>(inputs, xpk);

    // 12 KiB dynamic LDS pad -> >80 KiB/block => 1 block/CU => 256 blocks
    // co-resident on 256 CUs (grid-wide flag barrier is deadlock-free).
    lstm_persistent<<<dim3(NBLK), dim3(512), 12288, stream>>>(
        inputs, xpk, wpk, bf, bi, bc, bo, out, hpk0, hpk1, flags, use_xpk);
}

// Round 5
// 4803.473 us; speedup vs baseline: 1.9913x; 1.9913x over previous
//
#include <hip/hip_runtime.h>
#include <hip/hip_bf16.h>

#define TT  512
#define BB  64
#define NII 1024
#define NHH 1024
#define NBLK 256

typedef __attribute__((ext_vector_type(8))) short bf16x8;
typedef __attribute__((ext_vector_type(4))) float f32x4;

#define WPK_BYTES (256ull * 64 * 64 * 8 * 2)     // 16 MiB packed weights
#define FLG_BYTES (4096ull)                      // 256 u32 flags (padded)
#define HBUF_SHORTS (65536ull)                   // one packed-H buffer = 128 KiB
#define HRING_BYTES (512ull * HBUF_SHORTS * 2)   // 64 MiB step-unique ring
#define HPP_BYTES   (2ull * HBUF_SHORTS * 2)     // 256 KiB ping-pong fallback
#define XPK_BYTES (512ull * HBUF_SHORTS * 2)     // 64 MiB packed x frags

#define MFMA16 __builtin_amdgcn_mfma_f32_16x16x32_bf16
#define LD_AG(p)    __hip_atomic_load((p),  __ATOMIC_RELAXED, __HIP_MEMORY_SCOPE_AGENT)
#define ST_AG(p, v) __hip_atomic_store((p), (v), __ATOMIC_RELAXED, __HIP_MEMORY_SCOPE_AGENT)

__device__ __forceinline__ float sigmoidf_(float x) { return 1.0f / (1.0f + __expf(-x)); }

__device__ __forceinline__ short f2bf(float f) {
    union { __hip_bfloat16 b; short s; } u; u.b = __float2bfloat16(f); return u.s;
}

// pipelined coherent 16B load: two relaxed agent-scope u64 atomics (no
// per-load waitcnt drain, unlike volatile)
__device__ __forceinline__ bf16x8 ld_coh16(const short* p) {
    const unsigned long long* q = (const unsigned long long*)p;
    unsigned long long a = LD_AG(q);
    unsigned long long b = LD_AG(q + 1);
    union { unsigned long long u[2]; bf16x8 v; } u;
    u.u[0] = a; u.u[1] = b; return u.v;
}

// ---------------------------------------------------------------------------
// Pack 8 weight matrices into MFMA-B-fragment-major bf16 (verified r2-r4).
// ---------------------------------------------------------------------------
__global__ __launch_bounds__(256)
void pack_weights_kernel(const float* __restrict__ Wxf, const float* __restrict__ Whf,
                         const float* __restrict__ Wxi, const float* __restrict__ Whi,
                         const float* __restrict__ Wxc, const float* __restrict__ Whc,
                         const float* __restrict__ Wxo, const float* __restrict__ Who,
                         short* __restrict__ wpk)
{
    const int b = blockIdx.x;
    const int t = threadIdx.x;
    const float* Wx[4] = { Wxf, Wxi, Wxc, Wxo };
    const float* Wh[4] = { Whf, Whi, Whc, Who };

    for (int i = 0; i < 16; ++i) {
        const int pair = t + i * 256;
        const int kk = pair >> 6;
        const int l  = pair & 63;
        const int n  = l & 15;
        const int g  = n >> 2;
        const int col = b * 4 + (n & 3);
        const int kf0 = kk * 32 + (l >> 4) * 8;
        const float* src = (kf0 < 1024) ? (Wx[g] + (size_t)kf0 * NHH + col)
                                        : (Wh[g] + (size_t)(kf0 - 1024) * NHH + col);
        short v[8];
        #pragma unroll
        for (int e = 0; e < 8; ++e) v[e] = f2bf(src[(size_t)e * NHH]);
        short* dst = wpk + ((size_t)(b * 64 + kk) * 64 + l) * 8;
        *reinterpret_cast<bf16x8*>(dst) = *reinterpret_cast<bf16x8*>(v);
    }
}

// ---------------------------------------------------------------------------
// Pack x into bf16 A-fragments: xpk[t][mi][kk][l][8] (verified r3/r4).
// ---------------------------------------------------------------------------
__global__ __launch_bounds__(256)
void pack_x_kernel(const float* __restrict__ x, short* __restrict__ xpk)
{
    const int t = blockIdx.x;
    const float* xt = x + (size_t)t * BB * NII;
    short* dst = xpk + (size_t)t * HBUF_SHORTS;

    for (int i = 0; i < 32; ++i) {
        const int d  = threadIdx.x + i * 256;
        const int mi = d >> 11;
        const int kk = (d >> 6) & 31;
        const int l  = d & 63;
        const int m  = mi * 16 + (l & 15);
        const int k0 = kk * 32 + ((l >> 4) << 3);
        const float* s = xt + (size_t)m * NII + k0;
        f32x4 a0 = *reinterpret_cast<const f32x4*>(s);
        f32x4 a1 = *reinterpret_cast<const f32x4*>(s + 4);
        short v[8];
        #pragma unroll
        for (int e = 0; e < 4; ++e) { v[e] = f2bf(a0[e]); v[4 + e] = f2bf(a1[e]); }
        *reinterpret_cast<bf16x8*>(dst + (size_t)d * 8) = *reinterpret_cast<bf16x8*>(v);
    }
}

// ---------------------------------------------------------------------------
// Persistent LSTM. 256 blocks x 512 threads, 1 block/CU (LDS-forced).
// hmode=1: step-unique H ring -> plain cached H loads (pipelined, L2-served).
// hmode=0: ping-pong -> relaxed agent atomic H loads (pipelined, coherent).
// ---------------------------------------------------------------------------
__global__ __launch_bounds__(512, 1)
void lstm_persistent(const float* __restrict__ x,
                     const short* __restrict__ xpk,
                     const short* __restrict__ wpk,
                     const float* __restrict__ bfv, const float* __restrict__ biv,
                     const float* __restrict__ bcv, const float* __restrict__ bov,
                     float* __restrict__ out,
                     short* hbase,
                     unsigned* flags,
                     int hmode, int use_xpk)
{
    __shared__ short lds_w[64 * 64 * 8];   // 64 KiB weights, frag-major
    __shared__ float redx[4][64][4];
    __shared__ float redh[4][64][4];
    __shared__ float Cst[256];
    __shared__ short hstage[256];
    extern __shared__ char dynpad[];

    const int tid = threadIdx.x;
    const int w   = tid >> 6;
    const int l   = tid & 63;
    const int mi  = w & 3;
    const int kh  = w >> 2;
    const int b   = blockIdx.x;
    (void)dynpad;

    {
        const short* wsrc = wpk + (size_t)b * 32768;
        #pragma unroll
        for (int i = 0; i < 8; ++i) {
            const int c = tid + i * 512;
            *reinterpret_cast<bf16x8*>(&lds_w[c * 8]) =
                *reinterpret_cast<const bf16x8*>(&wsrc[(size_t)c * 8]);
        }
    }
    if (tid < 256) Cst[tid] = 0.0f;

    float B4[4] = {0.f, 0.f, 0.f, 0.f};
    if (tid < 256) {
        const int j = b * 4 + (tid & 3);
        B4[0] = bfv[j]; B4[1] = biv[j]; B4[2] = bcv[j]; B4[3] = bov[j];
    }
    __syncthreads();

    // packed-H write coords (j-range b*4..b*4+3 lies in one fragment octet)
    const int kk2 = b >> 3;
    const int lg  = (b >> 1) & 3;
    const int e0  = (b & 1) * 4;

    #pragma unroll 1
    for (int t = 0; t < TT; ++t) {
        const unsigned tv = (unsigned)t;
        const short* hcur = hbase + (size_t)(hmode ? t : (t & 1)) * HBUF_SHORTS;
        short*       hnxt = hbase + (size_t)(hmode ? (t + 1) : ((t + 1) & 1)) * HBUF_SHORTS;

        if (kh == 0) {
            f32x4 ac0 = {0,0,0,0}, ac1 = {0,0,0,0}, ac2 = {0,0,0,0}, ac3 = {0,0,0,0};
            const short* wl = &lds_w[(size_t)l * 8];
            if (use_xpk) {
                const short* ap = xpk + (size_t)t * HBUF_SHORTS + ((size_t)(mi * 32) * 64 + l) * 8;
                #pragma unroll 2
                for (int kk = 0; kk < 32; kk += 4) {
                    bf16x8 a0 = *reinterpret_cast<const bf16x8*>(ap);
                    bf16x8 b0 = *reinterpret_cast<const bf16x8*>(wl);
                    bf16x8 a1 = *reinterpret_cast<const bf16x8*>(ap + 512);
                    bf16x8 b1 = *reinterpret_cast<const bf16x8*>(wl + 512);
                    bf16x8 a2 = *reinterpret_cast<const bf16x8*>(ap + 1024);
                    bf16x8 b2 = *reinterpret_cast<const bf16x8*>(wl + 1024);
                    bf16x8 a3 = *reinterpret_cast<const bf16x8*>(ap + 1536);
                    bf16x8 b3 = *reinterpret_cast<const bf16x8*>(wl + 1536);
                    ac0 = MFMA16(a0, b0, ac0, 0, 0, 0);
                    ac1 = MFMA16(a1, b1, ac1, 0, 0, 0);
                    ac2 = MFMA16(a2, b2, ac2, 0, 0, 0);
                    ac3 = MFMA16(a3, b3, ac3, 0, 0, 0);
                    ap += 2048; wl += 2048;
                }
            } else {
                const float* apf = x + (size_t)t * BB * NII + (size_t)(mi * 16 + (l & 15)) * NII + (l >> 4) * 8;
                #pragma unroll 2
                for (int kk = 0; kk < 32; kk += 2) {
                    f32x4 a0 = *reinterpret_cast<const f32x4*>(apf);
                    f32x4 a1 = *reinterpret_cast<const f32x4*>(apf + 4);
                    bf16x8 b0 = *reinterpret_cast<const bf16x8*>(wl);
                    f32x4 a2 = *reinterpret_cast<const f32x4*>(apf + 32);
                    f32x4 a3 = *reinterpret_cast<const f32x4*>(apf + 36);
                    bf16x8 b1 = *reinterpret_cast<const bf16x8*>(wl + 512);
                    bf16x8 f0, f1;
                    f0[0]=f2bf(a0[0]); f0[1]=f2bf(a0[1]); f0[2]=f2bf(a0[2]); f0[3]=f2bf(a0[3]);
                    f0[4]=f2bf(a1[0]); f0[5]=f2bf(a1[1]); f0[6]=f2bf(a1[2]); f0[7]=f2bf(a1[3]);
                    f1[0]=f2bf(a2[0]); f1[1]=f2bf(a2[1]); f1[2]=f2bf(a2[2]); f1[3]=f2bf(a2[3]);
                    f1[4]=f2bf(a3[0]); f1[5]=f2bf(a3[1]); f1[6]=f2bf(a3[2]); f1[7]=f2bf(a3[3]);
                    ac0 = MFMA16(f0, b0, ac0, 0, 0, 0);
                    ac1 = MFMA16(f1, b1, ac1, 0, 0, 0);
                    apf += 64; wl += 1024;
                }
            }
            ac0[0]+=ac1[0]+ac2[0]+ac3[0]; ac0[1]+=ac1[1]+ac2[1]+ac3[1];
            ac0[2]+=ac1[2]+ac2[2]+ac3[2]; ac0[3]+=ac1[3]+ac2[3]+ac3[3];
            redx[mi][l][0]=ac0[0]; redx[mi][l][1]=ac0[1];
            redx[mi][l][2]=ac0[2]; redx[mi][l][3]=ac0[3];
        } else {
            // wait until every block has published H for this step
            const unsigned long long* q = (const unsigned long long*)flags + l * 2;
            for (;;) {
                unsigned long long aa = LD_AG(q);
                unsigned long long bb = LD_AG(q + 1);
                int ok = ((unsigned)aa >= tv) & ((unsigned)(aa >> 32) >= tv) &
                         ((unsigned)bb >= tv) & ((unsigned)(bb >> 32) >= tv);
                if (__all(ok)) break;
            }
            asm volatile("" ::: "memory");   // keep H loads below the poll

            f32x4 ac0 = {0,0,0,0}, ac1 = {0,0,0,0}, ac2 = {0,0,0,0}, ac3 = {0,0,0,0};
            const short* ap = hcur + ((size_t)(mi * 32) * 64 + l) * 8;
            const short* wl = &lds_w[((size_t)(32 * 64) + l) * 8];
            if (hmode) {
                // step-unique buffer: plain cached loads, fully pipelined
                #pragma unroll 2
                for (int kk = 0; kk < 32; kk += 4) {
                    bf16x8 a0 = *reinterpret_cast<const bf16x8*>(ap);
                    bf16x8 b0 = *reinterpret_cast<const bf16x8*>(wl);
                    bf16x8 a1 = *reinterpret_cast<const bf16x8*>(ap + 512);
                    bf16x8 b1 = *reinterpret_cast<const bf16x8*>(wl + 512);
                    bf16x8 a2 = *reinterpret_cast<const bf16x8*>(ap + 1024);
                    bf16x8 b2 = *reinterpret_cast<const bf16x8*>(wl + 1024);
                    bf16x8 a3 = *reinterpret_cast<const bf16x8*>(ap + 1536);
                    bf16x8 b3 = *reinterpret_cast<const bf16x8*>(wl + 1536);
                    ac0 = MFMA16(a0, b0, ac0, 0, 0, 0);
                    ac1 = MFMA16(a1, b1, ac1, 0, 0, 0);
                    ac2 = MFMA16(a2, b2, ac2, 0, 0, 0);
                    ac3 = MFMA16(a3, b3, ac3, 0, 0, 0);
                    ap += 2048; wl += 2048;
                }
            } else {
                // ping-pong fallback: coherent but pipelined atomic loads
                #pragma unroll 2
                for (int kk = 0; kk < 32; kk += 4) {
                    bf16x8 a0 = ld_coh16(ap);
                    bf16x8 b0 = *reinterpret_cast<const bf16x8*>(wl);
                    bf16x8 a1 = ld_coh16(ap + 512);
                    bf16x8 b1 = *reinterpret_cast<const bf16x8*>(wl + 512);
                    bf16x8 a2 = ld_coh16(ap + 1024);
                    bf16x8 b2 = *reinterpret_cast<const bf16x8*>(wl + 1024);
                    bf16x8 a3 = ld_coh16(ap + 1536);
                    bf16x8 b3 = *reinterpret_cast<const bf16x8*>(wl + 1536);
                    ac0 = MFMA16(a0, b0, ac0, 0, 0, 0);
                    ac1 = MFMA16(a1, b1, ac1, 0, 0, 0);
                    ac2 = MFMA16(a2, b2, ac2, 0, 0, 0);
                    ac3 = MFMA16(a3, b3, ac3, 0, 0, 0);
                    ap += 2048; wl += 2048;
                }
            }
            ac0[0]+=ac1[0]+ac2[0]+ac3[0]; ac0[1]+=ac1[1]+ac2[1]+ac3[1];
            ac0[2]+=ac1[2]+ac2[2]+ac3[2]; ac0[3]+=ac1[3]+ac2[3]+ac3[3];
            redh[mi][l][0]=ac0[0]; redh[mi][l][1]=ac0[1];
            redh[mi][l][2]=ac0[2]; redh[mi][l][3]=ac0[3];
        }
        __syncthreads();

        if (tid < 256) {
            const int m   = tid >> 2;
            const int jl  = tid & 3;
            const int mi2 = m >> 4, ml = m & 15;
            const int lr  = ml & 3;
            const int lb  = (ml >> 2) << 4;
            const int j   = b * 4 + jl;

            const float gf = redx[mi2][lb + jl][lr]      + redh[mi2][lb + jl][lr]      + B4[0];
            const float gi = redx[mi2][lb + 4 + jl][lr]  + redh[mi2][lb + 4 + jl][lr]  + B4[1];
            const float gc = redx[mi2][lb + 8 + jl][lr]  + redh[mi2][lb + 8 + jl][lr]  + B4[2];
            const float go = redx[mi2][lb + 12 + jl][lr] + redh[mi2][lb + 12 + jl][lr] + B4[3];

            const float F  = sigmoidf_(gf);
            const float I  = sigmoidf_(gi);
            const float Ct = tanhf(gc);
            const float O  = sigmoidf_(go);

            const float c  = Cst[tid];
            const float cn = F * c + I * Ct;
            const float hn = O * tanhf(cn);
            Cst[tid]    = cn;
            hstage[tid] = f2bf(hn);

            __builtin_nontemporal_store(hn, &out[(size_t)t * BB * NHH + (size_t)m * NHH + j]);
            if (t == TT - 1) {
                float* tail = out + (size_t)TT * BB * NHH;
                tail[(size_t)m * NHH + j]                    = hn;
                tail[(size_t)BB * NHH + (size_t)m * NHH + j] = cn;
            }
        }
        __syncthreads();

        if (w == 0 && t < TT - 1) {
            const int mi2 = l >> 4, ml = l & 15;
            const unsigned long long hv =
                *reinterpret_cast<const unsigned long long*>(&hstage[l * 4]);
            const size_t off = ((size_t)(mi2 * 32 + kk2) * 64 + lg * 16 + ml) * 8 + e0;
            ST_AG((unsigned long long*)(hnxt + off), hv);
            asm volatile("s_waitcnt vmcnt(0)" ::: "memory");
            if (l == 0)
                ST_AG(&flags[b], tv + 1u);
        }
    }
}

extern "C" void kernel_launch(void* const* d_in, const int* in_sizes, int n_in,
                              void* d_out, int out_size, void* d_ws, size_t ws_size,
                              hipStream_t stream) {
    const float* inputs = (const float*)d_in[0];
    const float* Wxf = (const float*)d_in[1],  *Whf = (const float*)d_in[2],  *bf = (const float*)d_in[3];
    const float* Wxi = (const float*)d_in[4],  *Whi = (const float*)d_in[5],  *bi = (const float*)d_in[6];
    const float* Wxc = (const float*)d_in[7],  *Whc = (const float*)d_in[8],  *bc = (const float*)d_in[9];
    const float* Wxo = (const float*)d_in[10], *Who = (const float*)d_in[11], *bo = (const float*)d_in[12];

    float* out = (float*)d_out;
    char*  wsb = (char*)d_ws;

    short*    wpk   = (short*)wsb;
    unsigned* flags = (unsigned*)(wsb + WPK_BYTES);
    short*    hbase = (short*)(wsb + WPK_BYTES + FLG_BYTES);

    const size_t base = WPK_BYTES + FLG_BYTES;
    int hmode, use_xpk;
    short* xpk;
    if (ws_size >= base + HRING_BYTES + XPK_BYTES) {
        hmode = 1; use_xpk = 1; xpk = (short*)(wsb + base + HRING_BYTES);
    } else if (ws_size >= base + HRING_BYTES) {
        hmode = 1; use_xpk = 0; xpk = nullptr;
    } else if (ws_size >= base + HPP_BYTES + XPK_BYTES) {
        hmode = 0; use_xpk = 1; xpk = (short*)(wsb + base + HPP_BYTES);
    } else {
        hmode = 0; use_xpk = 0; xpk = nullptr;
    }

    // zero flags + H buffer 0 (adjacent) every launch
    hipMemsetAsync(flags, 0, FLG_BYTES + HBUF_SHORTS * 2, stream);

    pack_weights_kernel<<<dim3(256), dim3(256), 0, stream>>>(
        Wxf, Whf, Wxi, Whi, Wxc, Whc, Wxo, Who, wpk);

    if (use_xpk)
        pack_x_kernel<<<dim3(TT), dim3(256), 0, stream>>>(inputs, xpk);

    // 12 KiB dynamic LDS pad -> >80 KiB/block => 1 block/CU => 256 blocks
    // co-resident on 256 CUs (grid-wide flag sync is deadlock-free).
    lstm_persistent<<<dim3(NBLK), dim3(512), 12288, stream>>>(
        inputs, xpk, wpk, bf, bi, bc, bo, out, hbase, flags, hmode, use_xpk);
}